// Round 1
// baseline (1075.936 us; speedup 1.0000x reference)
//
#include <hip/hip_runtime.h>

#define T_STEPS 500
#define BATCH   128
#define NINPUT  6
#define NH      500
#define THRV    1.0f
#define BETAV   0.5f
#define W2T_STRIDE 512
#define NG      4      // layer-2 output chunks of 128 neurons
#define NQ      4      // K-dimension quarters of 125

typedef unsigned long long ull;

// ---------------------------------------------------------------------------
// Transpose W2 [500][500] -> W2T [500][512] (padded stride), so that for a
// fixed input neuron i, the 500 outputs j are contiguous (coalesced float2).
// ---------------------------------------------------------------------------
__global__ void transpose_w2(const float* __restrict__ W2, float* __restrict__ W2T) {
  int idx = blockIdx.x * 256 + threadIdx.x;
  if (idx < NH * NH) {
    int i = idx / NH;        // input neuron
    int j = idx - i * NH;    // output neuron (contiguous for coalesced write)
    W2T[i * W2T_STRIDE + j] = W2[j * NH + i];
  }
}

// ---------------------------------------------------------------------------
// Phase A: layers 1+2 recurrence.
// grid = (BATCH, NG) blocks, 256 threads = 4 waves.
// Wave w of a block handles K-quarter [w*125, w*125+125): it computes layer-1
// membranes/spikes for those 125 neurons (self-contained), then sparsely
// accumulates W2T rows for active spikes into its partial cur2 for the
// block's 128-neuron j-chunk. Partials combined via LDS; all 4 waves
// redundantly keep the (identical) layer-2 membrane state. Spikes of layer 2
// are ballot-packed to s2bits[t][b][ng][2] (even-j mask, odd-j mask).
// ---------------------------------------------------------------------------
__global__ __launch_bounds__(256, 2) void phase_a(
    const float* __restrict__ x,     // [T][B][6]
    const float* __restrict__ W1,    // [500][6]
    const float* __restrict__ b1,    // [500]
    const float* __restrict__ b2,    // [500]
    const float* __restrict__ W2T,   // [500][512]
    ull* __restrict__ s2bits)        // [T][B][NG][2]
{
  const int b    = blockIdx.x;        // batch element
  const int ng   = blockIdx.y;        // j-chunk
  const int wid  = threadIdx.x >> 6;  // K-quarter
  const int lane = threadIdx.x & 63;

  const int qbase = wid * 125;

  // --- layer-1 static data: neurons qbase + lane + 64r, r=0..1 ---
  float w1r[2][6], b1r[2];
  float m1[2] = {0.f, 0.f};
  bool nvalid[2];
  for (int r = 0; r < 2; ++r) {
    int nloc = lane + (r << 6);
    nvalid[r] = (nloc < 125);
    int n = qbase + nloc;
    if (nvalid[r]) {
      const float* wp = W1 + n * NINPUT;
      #pragma unroll
      for (int k = 0; k < NINPUT; ++k) w1r[r][k] = wp[k];
      b1r[r] = b1[n];
    } else {
      #pragma unroll
      for (int k = 0; k < NINPUT; ++k) w1r[r][k] = 0.f;
      b1r[r] = 0.f;
    }
  }

  // --- layer-2 static data: columns j0 = ng*128 + 2*lane, j1 = j0+1 ---
  const int j0 = ng * 128 + 2 * lane;
  const int j1 = j0 + 1;
  const bool jv0 = (j0 < NH), jv1 = (j1 < NH);
  const float b2v0 = jv0 ? b2[j0] : 0.f;
  const float b2v1 = jv1 ? b2[j1] : 0.f;
  float m2a = 0.f, m2b = 0.f;

  const float* wrow = W2T + ng * 128 + 2 * lane;

  __shared__ float2 part[2][NQ][64];

  for (int t = 0; t < T_STEPS; ++t) {
    // broadcast input x[t][b][0..5]
    const float* xp = x + (size_t)(t * BATCH + b) * NINPUT;
    float x0 = xp[0], x1 = xp[1], x2 = xp[2],
          x3 = xp[3], x4 = xp[4], x5 = xp[5];

    // --- layer 1: leaky integrate-and-fire, ballot spikes ---
    ull mask[2];
    #pragma unroll
    for (int r = 0; r < 2; ++r) {
      float cur = b1r[r] + w1r[r][0]*x0 + w1r[r][1]*x1 + w1r[r][2]*x2
                        + w1r[r][3]*x3 + w1r[r][4]*x4 + w1r[r][5]*x5;
      float rst = (m1[r] > THRV) ? THRV : 0.f;
      m1[r] = BETAV * m1[r] + cur - rst;
      bool s = (m1[r] > THRV) && nvalid[r];
      mask[r] = __ballot(s);
    }

    // --- layer 2: sparse accumulate W2T rows for active spikes ---
    float acc0 = 0.f, acc1 = 0.f;
    #pragma unroll 1
    for (int half = 0; half < 2; ++half) {
      ull m = mask[half];
      const float* hb = wrow + (size_t)(qbase + (half << 6)) * W2T_STRIDE;
      while (m) {
        // peel up to 4 set bits -> 4 independent loads in flight
        int i0 = __builtin_ctzll(m); m &= m - 1;
        int i1 = 0, i2 = 0, i3 = 0;
        bool v1 = (m != 0);
        if (v1) { i1 = __builtin_ctzll(m); m &= m - 1; }
        bool v2 = (m != 0);
        if (v2) { i2 = __builtin_ctzll(m); m &= m - 1; }
        bool v3 = (m != 0);
        if (v3) { i3 = __builtin_ctzll(m); m &= m - 1; }
        float2 w0 = *(const float2*)(hb + (size_t)i0 * W2T_STRIDE);
        float2 w1v = *(const float2*)(hb + (size_t)i1 * W2T_STRIDE);
        float2 w2v = *(const float2*)(hb + (size_t)i2 * W2T_STRIDE);
        float2 w3v = *(const float2*)(hb + (size_t)i3 * W2T_STRIDE);
        acc0 += w0.x; acc1 += w0.y;
        if (v1) { acc0 += w1v.x; acc1 += w1v.y; }
        if (v2) { acc0 += w2v.x; acc1 += w2v.y; }
        if (v3) { acc0 += w3v.x; acc1 += w3v.y; }
      }
    }

    // --- combine the 4 K-quarter partials via LDS (double-buffered) ---
    int pb = t & 1;
    part[pb][wid][lane] = make_float2(acc0, acc1);
    __syncthreads();
    float2 p0 = part[pb][0][lane], p1 = part[pb][1][lane],
           p2 = part[pb][2][lane], p3 = part[pb][3][lane];
    float cur0 = ((p0.x + p1.x) + (p2.x + p3.x)) + b2v0;
    float cur1 = ((p0.y + p1.y) + (p2.y + p3.y)) + b2v1;

    // --- layer-2 LIF (redundant in all 4 waves; identical results) ---
    float rst0 = (m2a > THRV) ? THRV : 0.f;
    float rst1 = (m2b > THRV) ? THRV : 0.f;
    m2a = BETAV * m2a + cur0 - rst0;
    m2b = BETAV * m2b + cur1 - rst1;
    ull me = __ballot((m2a > THRV) && jv0);
    ull mo = __ballot((m2b > THRV) && jv1);
    if (threadIdx.x == 0) {
      ull* p = s2bits + ((size_t)(t * BATCH + b) * NG + ng) * 2;
      p[0] = me;
      p[1] = mo;
    }
  }
}

// ---------------------------------------------------------------------------
// Phase B: layer-3 recurrence. One wave per batch element.
// Lane l holds Wout values for j = g*128 + 2l and 2l+1 (g = 0..3), reads the
// packed s2 masks, conditionally accumulates, wave-reduces, updates m3,
// stores spk_rec and mem_rec.
// ---------------------------------------------------------------------------
__global__ __launch_bounds__(64) void phase_b(
    const ull* __restrict__ s2bits,  // [T][B][NG][2]
    const float* __restrict__ Wout,  // [2][500]
    const float* __restrict__ bout,  // [2]
    float* __restrict__ out)         // spk [T][B][2] then mem [T][B][2]
{
  const int b = blockIdx.x;
  const int lane = threadIdx.x;

  float we0[NG], wo0[NG], we1[NG], wo1[NG];
  #pragma unroll
  for (int g = 0; g < NG; ++g) {
    int j0 = g * 128 + 2 * lane, j1 = j0 + 1;
    we0[g] = (j0 < NH) ? Wout[j0] : 0.f;
    wo0[g] = (j1 < NH) ? Wout[j1] : 0.f;
    we1[g] = (j0 < NH) ? Wout[NH + j0] : 0.f;
    wo1[g] = (j1 < NH) ? Wout[NH + j1] : 0.f;
  }
  const float bo0 = bout[0], bo1 = bout[1];
  float m0 = 0.f, m1v = 0.f;

  for (int t = 0; t < T_STEPS; ++t) {
    const ull* p = s2bits + (size_t)(t * BATCH + b) * (NG * 2);
    float c0 = 0.f, c1 = 0.f;
    #pragma unroll
    for (int g = 0; g < NG; ++g) {
      ull me = p[2 * g], mo = p[2 * g + 1];
      if ((me >> lane) & 1ull) { c0 += we0[g]; c1 += we1[g]; }
      if ((mo >> lane) & 1ull) { c0 += wo0[g]; c1 += wo1[g]; }
    }
    #pragma unroll
    for (int off = 32; off; off >>= 1) {
      c0 += __shfl_xor(c0, off);
      c1 += __shfl_xor(c1, off);
    }
    c0 += bo0; c1 += bo1;

    float r0 = (m0 > THRV) ? THRV : 0.f;
    float r1 = (m1v > THRV) ? THRV : 0.f;
    m0  = BETAV * m0  + c0 - r0;
    m1v = BETAV * m1v + c1 - r1;

    if (lane == 0) {
      size_t o = (size_t)(t * BATCH + b) * 2;
      out[o]     = (m0  > THRV) ? 1.f : 0.f;
      out[o + 1] = (m1v > THRV) ? 1.f : 0.f;
      out[(size_t)T_STEPS * BATCH * 2 + o]     = m0;
      out[(size_t)T_STEPS * BATCH * 2 + o + 1] = m1v;
    }
  }
}

extern "C" void kernel_launch(void* const* d_in, const int* in_sizes, int n_in,
                              void* d_out, int out_size, void* d_ws, size_t ws_size,
                              hipStream_t stream) {
  const float* x    = (const float*)d_in[0];
  const float* W1   = (const float*)d_in[1];
  const float* b1   = (const float*)d_in[2];
  const float* W2   = (const float*)d_in[3];
  const float* b2   = (const float*)d_in[4];
  const float* Wout = (const float*)d_in[5];
  const float* bout = (const float*)d_in[6];
  float* out = (float*)d_out;

  // workspace layout: s2bits (4,096,000 B) | W2T (1,024,000 B)
  ull*   s2bits = (ull*)d_ws;
  float* W2T    = (float*)((char*)d_ws + (size_t)T_STEPS * BATCH * NG * 2 * sizeof(ull));

  transpose_w2<<<(NH * NH + 255) / 256, 256, 0, stream>>>(W2, W2T);
  phase_a<<<dim3(BATCH, NG), 256, 0, stream>>>(x, W1, b1, b2, W2T, s2bits);
  phase_b<<<BATCH, 64, 0, stream>>>(s2bits, Wout, bout, out);
}

// Round 4
// 710.327 us; speedup vs baseline: 1.5147x; 1.5147x over previous
//
#include <hip/hip_runtime.h>

#define T_STEPS 500
#define BATCH   128
#define NINPUT  6
#define NH      500
#define THRV    1.0f
#define BETAV   0.5f
#define W2T_STRIDE 512
#define NG      4      // layer-2 output chunks of 128 neurons
#define NW      8      // K-split: 8 waves, 64 rows (one mask word) each

typedef unsigned long long ull;

// ---------------------------------------------------------------------------
// Transpose W2 [500][500] -> W2T [500][512] (padded stride, pad zeroed).
// ---------------------------------------------------------------------------
__global__ void transpose_w2(const float* __restrict__ W2, float* __restrict__ W2T) {
  int idx = blockIdx.x * 256 + threadIdx.x;
  if (idx < NH * W2T_STRIDE) {
    int i = idx >> 9;          // input neuron (row of W2T)
    int j = idx & 511;         // output neuron (contiguous write)
    W2T[idx] = (j < NH) ? W2[j * NH + i] : 0.f;
  }
}

// ---------------------------------------------------------------------------
// Phase A: layers 1+2 recurrence, software-pipelined across timesteps.
// grid = (BATCH, NG), 512 threads = 8 waves. Wave w owns layer-1 neurons
// [64w, 64w+64) (one per lane -> ballot IS the mask word) and sparse-
// accumulates W2T rows for its active spikes into a partial cur2 for the
// block's 128-neuron j-chunk. Per iteration: prefetch x[t+2], compute
// mask[t+1], issue sparse loads for t+1, and -- while they are in flight --
// combine partials of t, update m2, store s2 bits. One barrier per step.
// ---------------------------------------------------------------------------
__global__ __launch_bounds__(512, 2) void phase_a(
    const float* __restrict__ x,     // [T][B][6]
    const float* __restrict__ W1,    // [500][6]
    const float* __restrict__ b1,    // [500]
    const float* __restrict__ b2,    // [500]
    const float* __restrict__ W2T,   // [500][512]
    ull* __restrict__ s2bits)        // [T][B][NG][2]
{
  const int b    = blockIdx.x;
  const int ng   = blockIdx.y;
  const int wid  = threadIdx.x >> 6;
  const int lane = threadIdx.x & 63;

  // --- layer-1 neuron for this lane ---
  const int n  = (wid << 6) + lane;
  const bool nv = (n < NH);
  float w1r[6], b1v;
  #pragma unroll
  for (int k = 0; k < 6; ++k) w1r[k] = nv ? W1[n * NINPUT + k] : 0.f;
  b1v = nv ? b1[n] : 0.f;
  float m1 = 0.f;

  // --- layer-2 columns j0, j0+1 for this lane ---
  const int j0 = ng * 128 + 2 * lane;
  const int j1 = j0 + 1;
  const bool jv0 = (j0 < NH), jv1 = (j1 < NH);
  const float b2v0 = jv0 ? b2[j0] : 0.f;
  const float b2v1 = jv1 ? b2[j1] : 0.f;
  float m2a = 0.f, m2b = 0.f;

  const float* wbase = W2T + (size_t)(wid << 6) * W2T_STRIDE + (ng * 128 + 2 * lane);

  __shared__ float2 part[2][NW][64];

  float xa[6], xb[6];

  // x loader (x rows are 24B -> float2-aligned)
  #define LOADX(tt, xr) do {                                             \
    const float* xp_ = x + (size_t)((tt) * BATCH + b) * NINPUT;          \
    float2 a_ = *(const float2*)xp_;                                     \
    float2 c_ = *(const float2*)(xp_ + 2);                               \
    float2 d_ = *(const float2*)(xp_ + 4);                               \
    xr[0]=a_.x; xr[1]=a_.y; xr[2]=c_.x; xr[3]=c_.y; xr[4]=d_.x; xr[5]=d_.y; \
  } while (0)

  // layer-1 LIF step from x regs; advances m1, returns spike mask word
  #define STEP1(xr, mask_out) do {                                       \
    float cur_ = b1v + w1r[0]*xr[0] + w1r[1]*xr[1] + w1r[2]*xr[2]        \
                     + w1r[3]*xr[3] + w1r[4]*xr[4] + w1r[5]*xr[5];       \
    float rst_ = (m1 > THRV) ? THRV : 0.f;                               \
    m1 = BETAV * m1 + cur_ - rst_;                                       \
    mask_out = __ballot((m1 > THRV) && nv);                              \
  } while (0)

  // sparse accumulate: 4-wide peel, rows in ascending order
  #define SPARSE(mm, a0, a1) do {                                        \
    ull m_ = (mm); a0 = 0.f; a1 = 0.f;                                   \
    while (m_) {                                                         \
      int i0 = __builtin_ctzll(m_); m_ &= m_ - 1;                        \
      int i1 = 0, i2 = 0, i3 = 0;                                        \
      bool v1 = (m_ != 0);                                               \
      if (v1) { i1 = __builtin_ctzll(m_); m_ &= m_ - 1; }                \
      bool v2 = (m_ != 0);                                               \
      if (v2) { i2 = __builtin_ctzll(m_); m_ &= m_ - 1; }                \
      bool v3 = (m_ != 0);                                               \
      if (v3) { i3 = __builtin_ctzll(m_); m_ &= m_ - 1; }                \
      float2 w0 = *(const float2*)(wbase + (size_t)i0 * W2T_STRIDE);     \
      float2 w1v = *(const float2*)(wbase + (size_t)i1 * W2T_STRIDE);    \
      float2 w2v = *(const float2*)(wbase + (size_t)i2 * W2T_STRIDE);    \
      float2 w3v = *(const float2*)(wbase + (size_t)i3 * W2T_STRIDE);    \
      a0 += w0.x; a1 += w0.y;                                            \
      if (v1) { a0 += w1v.x; a1 += w1v.y; }                              \
      if (v2) { a0 += w2v.x; a1 += w2v.y; }                              \
      if (v3) { a0 += w3v.x; a1 += w3v.y; }                              \
    }                                                                    \
  } while (0)

  // --- prologue: accumulate step 0, stage x[1] ---
  LOADX(0, xa);
  ull mask;
  STEP1(xa, mask);               // mask for t=0, m1 -> after step 0
  LOADX(1, xa);                  // xa now holds x[1]
  float a0, a1;
  SPARSE(mask, a0, a1);
  part[0][wid][lane] = make_float2(a0, a1);
  __syncthreads();

  for (int t = 0; t < T_STEPS - 1; ++t) {
    // 1. prefetch x[t+2]
    int tp = t + 2; if (tp > T_STEPS - 1) tp = T_STEPS - 1;
    LOADX(tp, xb);
    // 2. layer-1 mask for t+1 (short wave-local chain)
    STEP1(xa, mask);
    // 3. issue sparse loads for t+1 (latency overlaps step 4)
    SPARSE(mask, a0, a1);
    // 4. combine partials of t, layer-2 LIF, store spike bits
    const int pb = t & 1;
    float2 p0 = part[pb][0][lane], p1 = part[pb][1][lane],
           p2 = part[pb][2][lane], p3 = part[pb][3][lane],
           p4 = part[pb][4][lane], p5 = part[pb][5][lane],
           p6 = part[pb][6][lane], p7 = part[pb][7][lane];
    float cur0 = (((p0.x + p1.x) + (p2.x + p3.x)) +
                  ((p4.x + p5.x) + (p6.x + p7.x))) + b2v0;
    float cur1 = (((p0.y + p1.y) + (p2.y + p3.y)) +
                  ((p4.y + p5.y) + (p6.y + p7.y))) + b2v1;
    float rst0 = (m2a > THRV) ? THRV : 0.f;
    float rst1 = (m2b > THRV) ? THRV : 0.f;
    m2a = BETAV * m2a + cur0 - rst0;
    m2b = BETAV * m2b + cur1 - rst1;
    ull me = __ballot((m2a > THRV) && jv0);
    ull mo = __ballot((m2b > THRV) && jv1);
    if (threadIdx.x == 0) {
      ull* p = s2bits + ((size_t)(t * BATCH + b) * NG + ng) * 2;
      p[0] = me; p[1] = mo;
    }
    // 5. publish partials for t+1, one barrier
    part[pb ^ 1][wid][lane] = make_float2(a0, a1);
    __syncthreads();
    // 6. rotate x regs
    #pragma unroll
    for (int k = 0; k < 6; ++k) xa[k] = xb[k];
  }

  // --- epilogue: t = T_STEPS-1 ---
  {
    const int t = T_STEPS - 1;
    const int pb = t & 1;
    float2 p0 = part[pb][0][lane], p1 = part[pb][1][lane],
           p2 = part[pb][2][lane], p3 = part[pb][3][lane],
           p4 = part[pb][4][lane], p5 = part[pb][5][lane],
           p6 = part[pb][6][lane], p7 = part[pb][7][lane];
    float cur0 = (((p0.x + p1.x) + (p2.x + p3.x)) +
                  ((p4.x + p5.x) + (p6.x + p7.x))) + b2v0;
    float cur1 = (((p0.y + p1.y) + (p2.y + p3.y)) +
                  ((p4.y + p5.y) + (p6.y + p7.y))) + b2v1;
    float rst0 = (m2a > THRV) ? THRV : 0.f;
    float rst1 = (m2b > THRV) ? THRV : 0.f;
    m2a = BETAV * m2a + cur0 - rst0;
    m2b = BETAV * m2b + cur1 - rst1;
    ull me = __ballot((m2a > THRV) && jv0);
    ull mo = __ballot((m2b > THRV) && jv1);
    if (threadIdx.x == 0) {
      ull* p = s2bits + ((size_t)(t * BATCH + b) * NG + ng) * 2;
      p[0] = me; p[1] = mo;
    }
  }
  #undef LOADX
  #undef STEP1
  #undef SPARSE
}

// ---------------------------------------------------------------------------
// B1: cur3[t][b][2] = Wout . s2[t][b] -- fully parallel over (t,b).
// 4 waves/block, one (t,b) pair per wave.
// ---------------------------------------------------------------------------
__global__ __launch_bounds__(256) void cur3_kernel(
    const ull* __restrict__ s2bits,  // [T][B][NG][2]
    const float* __restrict__ Wout,  // [2][500]
    float* __restrict__ cur3)        // [T*B][2]
{
  const int wid  = threadIdx.x >> 6;
  const int lane = threadIdx.x & 63;
  const int pair = blockIdx.x * 4 + wid;   // t*BATCH + b
  if (pair >= T_STEPS * BATCH) return;

  float we0[NG], wo0[NG], we1[NG], wo1[NG];
  #pragma unroll
  for (int g = 0; g < NG; ++g) {
    int j0 = g * 128 + 2 * lane, j1 = j0 + 1;
    we0[g] = (j0 < NH) ? Wout[j0] : 0.f;
    wo0[g] = (j1 < NH) ? Wout[j1] : 0.f;
    we1[g] = (j0 < NH) ? Wout[NH + j0] : 0.f;
    wo1[g] = (j1 < NH) ? Wout[NH + j1] : 0.f;
  }

  const ull* p = s2bits + (size_t)pair * (NG * 2);
  float c0 = 0.f, c1 = 0.f;
  #pragma unroll
  for (int g = 0; g < NG; ++g) {
    ull me = p[2 * g], mo = p[2 * g + 1];
    if ((me >> lane) & 1ull) { c0 += we0[g]; c1 += we1[g]; }
    if ((mo >> lane) & 1ull) { c0 += wo0[g]; c1 += wo1[g]; }
  }
  #pragma unroll
  for (int off = 32; off; off >>= 1) {
    c0 += __shfl_xor(c0, off);
    c1 += __shfl_xor(c1, off);
  }
  if (lane == 0) *(float2*)(cur3 + (size_t)pair * 2) = make_float2(c0, c1);
}

// ---------------------------------------------------------------------------
// B2: serial m3 scan, one thread per batch element, 8-deep static prefetch.
// ---------------------------------------------------------------------------
__global__ __launch_bounds__(128) void scan3_kernel(
    const float* __restrict__ cur3,  // [T*B][2]
    const float* __restrict__ bout,  // [2]
    float* __restrict__ out)         // spk [T][B][2] then mem [T][B][2]
{
  const int b = threadIdx.x;
  const float bo0 = bout[0], bo1 = bout[1];
  float m0 = 0.f, m1v = 0.f;

  float2 cbuf[8], nbuf[8];
  #pragma unroll
  for (int k = 0; k < 8; ++k)
    cbuf[k] = *(const float2*)(cur3 + (size_t)(k * BATCH + b) * 2);

  for (int tc = 0; tc < T_STEPS; tc += 8) {
    #pragma unroll
    for (int k = 0; k < 8; ++k) {
      int tn = tc + 8 + k; if (tn > T_STEPS - 1) tn = T_STEPS - 1;
      nbuf[k] = *(const float2*)(cur3 + (size_t)(tn * BATCH + b) * 2);
    }
    #pragma unroll
    for (int k = 0; k < 8; ++k) {
      int t = tc + k;
      if (t < T_STEPS) {
        float c0 = cbuf[k].x + bo0, c1 = cbuf[k].y + bo1;
        float r0 = (m0  > THRV) ? THRV : 0.f;
        float r1 = (m1v > THRV) ? THRV : 0.f;
        m0  = BETAV * m0  + c0 - r0;
        m1v = BETAV * m1v + c1 - r1;
        size_t o = (size_t)(t * BATCH + b) * 2;
        out[o]     = (m0  > THRV) ? 1.f : 0.f;
        out[o + 1] = (m1v > THRV) ? 1.f : 0.f;
        out[(size_t)T_STEPS * BATCH * 2 + o]     = m0;
        out[(size_t)T_STEPS * BATCH * 2 + o + 1] = m1v;
      }
    }
    #pragma unroll
    for (int k = 0; k < 8; ++k) cbuf[k] = nbuf[k];
  }
}

extern "C" void kernel_launch(void* const* d_in, const int* in_sizes, int n_in,
                              void* d_out, int out_size, void* d_ws, size_t ws_size,
                              hipStream_t stream) {
  const float* x    = (const float*)d_in[0];
  const float* W1   = (const float*)d_in[1];
  const float* b1   = (const float*)d_in[2];
  const float* W2   = (const float*)d_in[3];
  const float* b2   = (const float*)d_in[4];
  const float* Wout = (const float*)d_in[5];
  const float* bout = (const float*)d_in[6];
  float* out = (float*)d_out;

  // ws layout: s2bits [0, 4.096 MB) | W2T [4.096, 5.12 MB)
  // cur3 (512 KB) reuses the W2T region (W2T dead after phase_a).
  ull*   s2bits = (ull*)d_ws;
  float* W2T    = (float*)((char*)d_ws + (size_t)T_STEPS * BATCH * NG * 2 * sizeof(ull));
  float* cur3   = W2T;

  transpose_w2<<<(NH * W2T_STRIDE + 255) / 256, 256, 0, stream>>>(W2, W2T);
  phase_a<<<dim3(BATCH, NG), 512, 0, stream>>>(x, W1, b1, b2, W2T, s2bits);
  cur3_kernel<<<(T_STEPS * BATCH + 3) / 4, 256, 0, stream>>>(s2bits, Wout, cur3);
  scan3_kernel<<<1, 128, 0, stream>>>(cur3, bout, out);
}